// Round 1
// baseline (1568.407 us; speedup 1.0000x reference)
//
#include <hip/hip_runtime.h>
#include <math.h>

#define N_NODES 100000
#define N_EDGES 3200000
#define DIM_IN  128
#define DIM_HID 64
#define DIM_OUT 40

// ---------------- GEMM1: h = x @ W1   [N,128] x [128,64] -> [N,64] ----------
// 256 threads/block = 4 rows x 64 cols. W1 staged in LDS (32 KB).
__global__ __launch_bounds__(256) void gemm1_kernel(
    const float* __restrict__ x, const float* __restrict__ W1,
    float* __restrict__ h) {
  __shared__ float w[DIM_IN * DIM_HID];
  for (int i = threadIdx.x; i < DIM_IN * DIM_HID; i += 256) w[i] = W1[i];
  __syncthreads();
  const int row = blockIdx.x * 4 + (threadIdx.x >> 6);
  const int col = threadIdx.x & 63;
  if (row >= N_NODES) return;
  const float* xr = x + (size_t)row * DIM_IN;
  float acc = 0.f;
#pragma unroll 8
  for (int k = 0; k < DIM_IN; ++k) acc = fmaf(xr[k], w[k * DIM_HID + col], acc);
  h[(size_t)row * DIM_HID + col] = acc;
}

// ---------------- SPMM: out[dst] += w * h[src], one thread per (edge,dim) ---
template <int D, int BLOCK>
__global__ __launch_bounds__(BLOCK) void spmm_kernel(
    const int* __restrict__ dst, const int* __restrict__ src,
    const float* __restrict__ ew, const float* __restrict__ h,
    float* __restrict__ out) {
  const long long tid = (long long)blockIdx.x * BLOCK + threadIdx.x;
  const int e = (int)(tid / D);
  const int d = (int)(tid % D);
  if (e >= N_EDGES) return;
  const int s = src[e];
  const int t = dst[e];
  const float v = ew[e] * h[(size_t)s * D + d];
  atomicAdd(&out[(size_t)t * D + d], v);
}

// ---------------- GEMM2: h2 = relu(agg) @ W2   [N,64] x [64,40] -> [N,40] ---
// 320 threads/block = 8 rows x 40 cols. W2 staged in LDS (10 KB).
__global__ __launch_bounds__(320) void gemm2_kernel(
    const float* __restrict__ hin, const float* __restrict__ W2,
    float* __restrict__ h2) {
  __shared__ float w[DIM_HID * DIM_OUT];
  for (int i = threadIdx.x; i < DIM_HID * DIM_OUT; i += 320) w[i] = W2[i];
  __syncthreads();
  const int row = blockIdx.x * 8 + threadIdx.x / DIM_OUT;
  const int col = threadIdx.x % DIM_OUT;
  if (row >= N_NODES) return;
  const float* hr = hin + (size_t)row * DIM_HID;
  float acc = 0.f;
#pragma unroll 8
  for (int k = 0; k < DIM_HID; ++k)
    acc = fmaf(fmaxf(hr[k], 0.f), w[k * DIM_OUT + col], acc);
  h2[(size_t)row * DIM_OUT + col] = acc;
}

// ---------------- log_softmax over rows of 40 -------------------------------
// 256 threads/block = 4 waves = 4 rows; lanes 0..39 active per row.
__global__ __launch_bounds__(256) void logsoftmax_kernel(
    const float* __restrict__ in, float* __restrict__ out) {
  const int row = blockIdx.x * 4 + (threadIdx.x >> 6);
  const int lane = threadIdx.x & 63;
  if (row >= N_NODES) return;
  const float v = (lane < DIM_OUT) ? in[(size_t)row * DIM_OUT + lane] : -INFINITY;
  float m = v;
#pragma unroll
  for (int off = 32; off > 0; off >>= 1) m = fmaxf(m, __shfl_xor(m, off));
  const float e = (lane < DIM_OUT) ? expf(v - m) : 0.f;
  float s = e;
#pragma unroll
  for (int off = 32; off > 0; off >>= 1) s += __shfl_xor(s, off);
  const float ls = logf(s);
  if (lane < DIM_OUT) out[(size_t)row * DIM_OUT + lane] = v - m - ls;
}

extern "C" void kernel_launch(void* const* d_in, const int* in_sizes, int n_in,
                              void* d_out, int out_size, void* d_ws, size_t ws_size,
                              hipStream_t stream) {
  const float* x  = (const float*)d_in[0];
  const int*   ei = (const int*)d_in[1];   // [2, E]: first E = dst, next E = src
  const float* ew = (const float*)d_in[2];
  const float* W1 = (const float*)d_in[3];
  const float* W2 = (const float*)d_in[4];
  float* out = (float*)d_out;

  const int* dst = ei;
  const int* src = ei + N_EDGES;

  // Workspace layout (reused across phases):
  //   bufA: N*64 floats  (h, then reused for h2 [N*40])
  //   bufB: N*64 floats  (agg1, then reused for agg2 [N*40])
  float* bufA = (float*)d_ws;
  float* bufB = bufA + (size_t)N_NODES * DIM_HID;

  // 1) zero agg1
  hipMemsetAsync(bufB, 0, (size_t)N_NODES * DIM_HID * sizeof(float), stream);

  // 2) h = x @ W1
  gemm1_kernel<<<(N_NODES + 3) / 4, 256, 0, stream>>>(x, W1, bufA);

  // 3) agg1[dst] += w * h[src]
  {
    const long long total = (long long)N_EDGES * DIM_HID;
    const int grid = (int)((total + 255) / 256);
    spmm_kernel<DIM_HID, 256><<<grid, 256, 0, stream>>>(dst, src, ew, bufA, bufB);
  }

  // 4) h2 = relu(agg1) @ W2   (h2 overwrites bufA; agg1 read then dead)
  gemm2_kernel<<<(N_NODES + 7) / 8, 320, 0, stream>>>(bufB, W2, bufA);

  // 5) zero agg2 (reuses bufB; stream order guarantees gemm2 done reading)
  hipMemsetAsync(bufB, 0, (size_t)N_NODES * DIM_OUT * sizeof(float), stream);

  // 6) agg2[dst] += w * h2[src]
  {
    const long long total = (long long)N_EDGES * DIM_OUT;
    const int grid = (int)((total + 319) / 320);
    spmm_kernel<DIM_OUT, 320><<<grid, 320, 0, stream>>>(dst, src, ew, bufA, bufB);
  }

  // 7) out = log_softmax(agg2, axis=1)
  logsoftmax_kernel<<<(N_NODES + 3) / 4, 256, 0, stream>>>(bufB, out);
}

// Round 2
// 914.795 us; speedup vs baseline: 1.7145x; 1.7145x over previous
//
#include <hip/hip_runtime.h>
#include <math.h>

#define N_NODES 100000
#define N_EDGES 3200000
#define DIM_IN  128
#define DIM_HID 64
#define DIM_OUT 40

#define SCAN_CHUNK 1024
#define NB1 ((N_NODES + SCAN_CHUNK - 1) / SCAN_CHUNK)   // 98

// ---------------- CSR build ------------------------------------------------
__global__ __launch_bounds__(256) void deg_kernel(
    const int* __restrict__ dst, int* __restrict__ deg) {
  const int e = blockIdx.x * 256 + threadIdx.x;
  if (e < N_EDGES) atomicAdd(&deg[dst[e]], 1);
}

__device__ inline int wave_incl_scan(int v, int lane) {
#pragma unroll
  for (int off = 1; off < 64; off <<= 1) {
    int n = __shfl_up(v, off);
    if (lane >= off) v += n;
  }
  return v;
}

// Block b scans deg[b*1024 .. b*1024+1023] -> exclusive partials + block sum.
__global__ __launch_bounds__(256) void scan1_kernel(
    const int* __restrict__ deg, int* __restrict__ partial,
    int* __restrict__ bsum) {
  const int t = threadIdx.x, b = blockIdx.x;
  const int base = b * SCAN_CHUNK + t * 4;
  int v[4]; int s = 0;
#pragma unroll
  for (int j = 0; j < 4; ++j) {
    const int idx = base + j;
    v[j] = (idx < N_NODES) ? deg[idx] : 0;
    s += v[j];
  }
  const int lane = t & 63, w = t >> 6;
  const int incl = wave_incl_scan(s, lane);
  __shared__ int wsum[4];
  if (lane == 63) wsum[w] = incl;
  __syncthreads();
  int woff = 0;
  for (int k = 0; k < w; ++k) woff += wsum[k];
  int run = incl - s + woff;  // exclusive prefix for this thread's first item
#pragma unroll
  for (int j = 0; j < 4; ++j) {
    const int idx = base + j;
    if (idx < N_NODES) partial[idx] = run;
    run += v[j];
  }
  if (t == 255) bsum[b] = run;  // block total
}

// Single block: exclusive scan of the 98 block sums.
__global__ __launch_bounds__(128) void scan2_kernel(
    const int* __restrict__ bsum, int* __restrict__ boff) {
  __shared__ int sh[128];
  const int t = threadIdx.x;
  const int v = (t < NB1) ? bsum[t] : 0;
  sh[t] = v;
  __syncthreads();
  for (int off = 1; off < 128; off <<= 1) {
    int a = 0;
    if (t >= off) a = sh[t - off];
    __syncthreads();
    sh[t] += a;
    __syncthreads();
  }
  if (t < NB1) boff[t] = sh[t] - v;
}

__global__ __launch_bounds__(256) void scan3_kernel(
    const int* __restrict__ partial, const int* __restrict__ boff,
    int* __restrict__ ptr, int* __restrict__ cursor) {
  const int i = blockIdx.x * 256 + threadIdx.x;
  if (i < N_NODES) {
    const int p = partial[i] + boff[i / SCAN_CHUNK];
    ptr[i] = p;
    cursor[i] = p;
  }
  if (i == 0) ptr[N_NODES] = N_EDGES;
}

__global__ __launch_bounds__(256) void scatter_kernel(
    const int* __restrict__ dst, const int* __restrict__ src,
    const float* __restrict__ ew, int* __restrict__ cursor,
    int2* __restrict__ packed) {
  const int e = blockIdx.x * 256 + threadIdx.x;
  if (e >= N_EDGES) return;
  const int t = dst[e];
  const int pos = atomicAdd(&cursor[t], 1);
  int2 p;
  p.x = src[e];
  p.y = __float_as_int(ew[e]);
  packed[pos] = p;
}

// ---------------- GEMM1: h = x @ W1   [N,128] x [128,64] -> [N,64] ----------
__global__ __launch_bounds__(256) void gemm1_kernel(
    const float* __restrict__ x, const float* __restrict__ W1,
    float* __restrict__ h) {
  __shared__ float w[DIM_IN * DIM_HID];
  for (int i = threadIdx.x; i < DIM_IN * DIM_HID; i += 256) w[i] = W1[i];
  __syncthreads();
  const int row = blockIdx.x * 4 + (threadIdx.x >> 6);
  const int col = threadIdx.x & 63;
  if (row >= N_NODES) return;
  const float* xr = x + (size_t)row * DIM_IN;
  float acc = 0.f;
#pragma unroll 8
  for (int k = 0; k < DIM_IN; ++k) acc = fmaf(xr[k], w[k * DIM_HID + col], acc);
  h[(size_t)row * DIM_HID + col] = acc;
}

// ---------------- SPMM1 (CSR): agg[n,d] = sum_e w_e * h[src_e, d], D=64 -----
// One wave per node; lane = dim. 4-way unrolled for MLP.
__global__ __launch_bounds__(256) void spmm_csr64_kernel(
    const int* __restrict__ ptr, const int2* __restrict__ packed,
    const float* __restrict__ h, float* __restrict__ out) {
  const int node = blockIdx.x * 4 + (threadIdx.x >> 6);
  const int lane = threadIdx.x & 63;
  if (node >= N_NODES) return;
  int e = ptr[node];
  const int end = ptr[node + 1];
  float acc = 0.f;
  for (; e + 4 <= end; e += 4) {
    const int2 p0 = packed[e], p1 = packed[e + 1];
    const int2 p2 = packed[e + 2], p3 = packed[e + 3];
    const float a0 = h[(size_t)p0.x * DIM_HID + lane];
    const float a1 = h[(size_t)p1.x * DIM_HID + lane];
    const float a2 = h[(size_t)p2.x * DIM_HID + lane];
    const float a3 = h[(size_t)p3.x * DIM_HID + lane];
    acc = fmaf(__int_as_float(p0.y), a0, acc);
    acc = fmaf(__int_as_float(p1.y), a1, acc);
    acc = fmaf(__int_as_float(p2.y), a2, acc);
    acc = fmaf(__int_as_float(p3.y), a3, acc);
  }
  for (; e < end; ++e) {
    const int2 p = packed[e];
    acc = fmaf(__int_as_float(p.y), h[(size_t)p.x * DIM_HID + lane], acc);
  }
  out[(size_t)node * DIM_HID + lane] = acc;
}

// ---------------- GEMM2: h2 = relu(agg) @ W2   [N,64] x [64,40] -> [N,40] ---
__global__ __launch_bounds__(320) void gemm2_kernel(
    const float* __restrict__ hin, const float* __restrict__ W2,
    float* __restrict__ h2) {
  __shared__ float w[DIM_HID * DIM_OUT];
  for (int i = threadIdx.x; i < DIM_HID * DIM_OUT; i += 320) w[i] = W2[i];
  __syncthreads();
  const int row = blockIdx.x * 8 + threadIdx.x / DIM_OUT;
  const int col = threadIdx.x % DIM_OUT;
  if (row >= N_NODES) return;
  const float* hr = hin + (size_t)row * DIM_HID;
  float acc = 0.f;
#pragma unroll 8
  for (int k = 0; k < DIM_HID; ++k)
    acc = fmaf(fmaxf(hr[k], 0.f), w[k * DIM_OUT + col], acc);
  h2[(size_t)row * DIM_OUT + col] = acc;
}

// ------- SPMM2 (CSR, D=40) + fused log_softmax ------------------------------
// One wave per node; lanes 0..39 = dims; lanes 40..63 clamp address (broadcast)
// so the gather stays within the 160B row.
__global__ __launch_bounds__(256) void spmm_csr40_lsm_kernel(
    const int* __restrict__ ptr, const int2* __restrict__ packed,
    const float* __restrict__ h2, float* __restrict__ out) {
  const int node = blockIdx.x * 4 + (threadIdx.x >> 6);
  const int lane = threadIdx.x & 63;
  if (node >= N_NODES) return;
  const int l = (lane < DIM_OUT) ? lane : (DIM_OUT - 1);
  int e = ptr[node];
  const int end = ptr[node + 1];
  float acc = 0.f;
  for (; e + 4 <= end; e += 4) {
    const int2 p0 = packed[e], p1 = packed[e + 1];
    const int2 p2 = packed[e + 2], p3 = packed[e + 3];
    const float a0 = h2[(size_t)p0.x * DIM_OUT + l];
    const float a1 = h2[(size_t)p1.x * DIM_OUT + l];
    const float a2 = h2[(size_t)p2.x * DIM_OUT + l];
    const float a3 = h2[(size_t)p3.x * DIM_OUT + l];
    acc = fmaf(__int_as_float(p0.y), a0, acc);
    acc = fmaf(__int_as_float(p1.y), a1, acc);
    acc = fmaf(__int_as_float(p2.y), a2, acc);
    acc = fmaf(__int_as_float(p3.y), a3, acc);
  }
  for (; e < end; ++e) {
    const int2 p = packed[e];
    acc = fmaf(__int_as_float(p.y), h2[(size_t)p.x * DIM_OUT + l], acc);
  }
  // log_softmax across lanes 0..39
  const bool act = (lane < DIM_OUT);
  const float v = act ? acc : -INFINITY;
  float m = v;
#pragma unroll
  for (int off = 32; off > 0; off >>= 1) m = fmaxf(m, __shfl_xor(m, off));
  const float ex = act ? expf(v - m) : 0.f;
  float s = ex;
#pragma unroll
  for (int off = 32; off > 0; off >>= 1) s += __shfl_xor(s, off);
  const float ls = logf(s);
  if (act) out[(size_t)node * DIM_OUT + lane] = v - m - ls;
}

extern "C" void kernel_launch(void* const* d_in, const int* in_sizes, int n_in,
                              void* d_out, int out_size, void* d_ws, size_t ws_size,
                              hipStream_t stream) {
  const float* x  = (const float*)d_in[0];
  const int*   ei = (const int*)d_in[1];   // [2, E]: first E = dst, next E = src
  const float* ew = (const float*)d_in[2];
  const float* W1 = (const float*)d_in[3];
  const float* W2 = (const float*)d_in[4];
  float* out = (float*)d_out;

  const int* dst = ei;
  const int* src = ei + N_EDGES;

  // --------- workspace layout (bytes) ---------
  char* p = (char*)d_ws;
  int2*  packed  = (int2*)p;                 p += (size_t)N_EDGES * 8;        // 25.6 MB
  float* bufA    = (float*)p;                p += (size_t)N_NODES * DIM_HID * 4; // 25.6 MB (h, then h2)
  float* bufB    = (float*)p;                p += (size_t)N_NODES * DIM_HID * 4; // 25.6 MB (agg1)
  int*   deg     = (int*)p;                  p += (size_t)N_NODES * 4;
  int*   partial = (int*)p;                  p += (size_t)N_NODES * 4;
  int*   ptr     = (int*)p;                  p += (size_t)(N_NODES + 8) * 4;
  int*   cursor  = (int*)p;                  p += (size_t)N_NODES * 4;
  int*   bsum    = (int*)p;                  p += 512;
  int*   boff    = (int*)p;                  p += 512;

  const int egrid = (N_EDGES + 255) / 256;          // 12500
  const int ngrid4 = (N_NODES + 3) / 4;             // 25000

  // --------- CSR build ---------
  hipMemsetAsync(deg, 0, (size_t)N_NODES * 4, stream);
  deg_kernel<<<egrid, 256, 0, stream>>>(dst, deg);
  scan1_kernel<<<NB1, 256, 0, stream>>>(deg, partial, bsum);
  scan2_kernel<<<1, 128, 0, stream>>>(bsum, boff);
  scan3_kernel<<<(N_NODES + 255) / 256, 256, 0, stream>>>(partial, boff, ptr, cursor);
  scatter_kernel<<<egrid, 256, 0, stream>>>(dst, src, ew, cursor, packed);

  // --------- layer 1 ---------
  gemm1_kernel<<<ngrid4, 256, 0, stream>>>(x, W1, bufA);
  spmm_csr64_kernel<<<ngrid4, 256, 0, stream>>>(ptr, packed, bufA, bufB);

  // --------- layer 2 (h2 overwrites bufA) ---------
  gemm2_kernel<<<(N_NODES + 7) / 8, 320, 0, stream>>>(bufB, W2, bufA);
  spmm_csr40_lsm_kernel<<<ngrid4, 256, 0, stream>>>(ptr, packed, bufA, out);
}